// Round 5
// baseline (404.777 us; speedup 1.0000x reference)
//
#include <hip/hip_runtime.h>

// Simple_Cross2: x[16384,512] -> cross -> 2048 -> 2048 -> 1024 -> 512 -> 1
// bf16 MFMA (16x16x32) GEMMs, fp32 accumulate, fused bias+relu.
// R2: BK=64 + XOR swizzle -> 0 bank conflicts.
// R3: 64x128 wave tile, 8-wave 2-phase -> G2 119us.
// R8-R11: 8-wave 256x256 counted-vmcnt schedules -> G2 120-130us, MfmaUtil
//      44-50% regardless of barrier count/retiming. Arithmetic: 8 waves x
//      48 ds_read_b128/iter = 4608cy/CU + 512cy ds-writes vs 4966cy MFMA ->
//      LDS port co-critical; 50% = serialization ceiling. Wave tile 128x64
//      has A-amp 4x, B-amp 2x (192KB read per 64KB staged).
// R12: FAT-WAVE rewrite: 4 waves (256 thr), wave tile 128x128 (2x2 grid),
//      amp 2x/2x -> 128 reads/iter/CU (1536cy) << MFMA 4966cy. 1 wave/SIMD:
//      hiding via in-wave ILP with counted waits -- per K-tile:
//      {RD k1 | MFMA(k0)x64 | lgkm0 vmcnt(0) BAR | restage | RD k0' |
//       MFMA(k1)x64}. Every wait issued >=1241cy ahead. acc 256 + frags 128
//      ~= 410 VGPR (unified file, launch_bounds(256,1) -> 512 cap).

#define BK 64

typedef __bf16 bf16x8 __attribute__((ext_vector_type(8)));
typedef float  f32x4  __attribute__((ext_vector_type(4)));
typedef unsigned short u16x4 __attribute__((ext_vector_type(4)));

__device__ __forceinline__ unsigned short f2bf(float f) {
    unsigned int u = __builtin_bit_cast(unsigned int, f);
    u += 0x7fffu + ((u >> 16) & 1u);          // round-to-nearest-even
    return (unsigned short)(u >> 16);
}

__device__ __forceinline__ void async16(const void* g, void* l) {
    __builtin_amdgcn_global_load_lds(
        (const __attribute__((address_space(1))) unsigned int*)g,
        (__attribute__((address_space(3))) unsigned int*)l,
        16, 0, 0);
}

#define BAR()   __builtin_amdgcn_s_barrier()
#define LGKM0() asm volatile("s_waitcnt lgkmcnt(0)" ::: "memory")
#define VMW(n)  asm volatile("s_waitcnt vmcnt(" #n ")" ::: "memory")

// read 8 A-frags + 8 B-frags for one k-step (16 x ds_read_b128)
#define RDFRAG(AF, BF, ABP, BBP, BUF) do { _Pragma("unroll") \
    for (int f = 0; f < 8; ++f) AF[f] = *(const bf16x8*)((ABP) + (BUF) + f * 2048); \
    _Pragma("unroll") \
    for (int g = 0; g < 8; ++g) BF[g] = *(const bf16x8*)((BBP) + (BUF) + g * 2048); } while (0)

// 64 independent MFMAs (8x8 outer product), all distinct acc -> pipe stays fed
#define MM64(AF, BF) do { _Pragma("unroll") \
    for (int f = 0; f < 8; ++f) _Pragma("unroll") \
    for (int g = 0; g < 8; ++g) \
        acc[f][g] = __builtin_amdgcn_mfma_f32_16x16x32_bf16( \
            AF[f], BF[g], acc[f][g], 0, 0, 0); } while (0)

// ---------------------------------------------------------------------------
// Fat-wave 256x256 tile, BK=64, 256 threads (4 waves, 2x2 grid, 128x128/wave).
// C = relu(A[M,K]*B[N,K]^T + bias). LDS 128 KiB:
//   A: bufX {rows0-127 @0, rows128-255 @16K}, bufY @32K; B: same @ +64K.
// Within each [128][64] half: elem(row,c) at row*64 + (((c>>3)^(row&7))*8+(c&7)).
// ---------------------------------------------------------------------------
__global__ __launch_bounds__(256, 1)
void gemm_fat_bias_relu(const unsigned short* __restrict__ A,
                        const unsigned short* __restrict__ B,
                        const float* __restrict__ bias,
                        unsigned short* __restrict__ C,
                        int M, int N, int K)
{
    __shared__ __align__(16) unsigned short L[65536];   // 128 KiB

    const int tid  = threadIdx.x;
    const int lane = tid & 63;
    const int wave = tid >> 6;          // 0..3
    const int quad = lane >> 4;
    const int l16  = lane & 15;
    const int wr   = wave >> 1;          // 0..1  (row half)
    const int wcol = wave & 1;           // 0..1  (col half)

    const int bm = blockIdx.x * 256;
    const int bn = blockIdx.y * 256;

    // ---- staging: pre-swizzled global source, linear LDS dest.
    // thread t covers rows trow + i*32 (i=0..3) of a 128-row half; 16B each.
    const int trow = tid >> 3;                        // 0..31
    const int cswz = ((tid & 7) ^ (trow & 7)) * 8;    // (row&7) invariant in i
    const unsigned short* gaL = A + (size_t)(bm + trow) * K + cswz;
    const unsigned short* gaH = gaL + (size_t)128 * K;
    const unsigned short* gbL = B + (size_t)(bn + trow) * K + cswz;
    const unsigned short* gbH = gbL + (size_t)128 * K;

    auto stage4 = [&](const unsigned short* g, int regionByte, int ko) {
#pragma unroll
        for (int i = 0; i < 4; ++i)
            async16(g + (size_t)(i * 32) * K + ko,
                    (char*)L + regionByte + tid * 16 + i * 4096);
    };

    // ---- fragment read base pointers (c0/c1 = k-halves, proven swizzle)
    const int xa = l16 & 7;
    const int c0 = (quad ^ xa) * 8;
    const int c1 = ((quad ^ 4) ^ xa) * 8;
    const char* aB0 = (const char*)L + wr * 16384 + (l16 * 64 + c0) * 2;
    const char* aB1 = (const char*)L + wr * 16384 + (l16 * 64 + c1) * 2;
    const char* bB0 = (const char*)L + 65536 + wcol * 16384 + (l16 * 64 + c0) * 2;
    const char* bB1 = (const char*)L + 65536 + wcol * 16384 + (l16 * 64 + c1) * 2;

    f32x4 acc[8][8] = {};                 // 256 regs (AGPR side)
    bf16x8 af0[8], bf0[8], af1[8], bf1[8];

    // ---- prologue: t0 -> bufX, t1 -> bufY (16 loads each)
    stage4(gaL, 0, 0);     stage4(gaH, 16384, 0);
    stage4(gbL, 65536, 0); stage4(gbH, 81920, 0);
    stage4(gaL, 32768, 64);  stage4(gaH, 49152, 64);
    stage4(gbL, 98304, 64);  stage4(gbH, 114688, 64);
    VMW(16);                 // t0 landed; t1's 16 in flight
    BAR();
    RDFRAG(af0, bf0, aB0, bB0, 0);        // X.k0

    const int nIter = K >> 7;             // 2 K-tiles per iter
    for (int i = 0; i < nIter; ++i) {
        int k2 = (2 * i + 2) << 6; if (k2 >= K) k2 -= K;   // tail wrap
        int k3 = (2 * i + 3) << 6; if (k3 >= K) k3 -= K;

        // ---- tile 2i in bufX
        RDFRAG(af1, bf1, aB1, bB1, 0);    // X.k1 (completes under MFMA below)
        MM64(af0, bf0);                   // 64 MFMA (~1241cy)
        LGKM0();                          // X fully read (this wave)
        VMW(0);                           // t+1 (bufY) landed (this wave)
        BAR();                            // ...for ALL waves
        stage4(gaL, 0, k2);     stage4(gaH, 16384, k2);      // t+2 -> X
        stage4(gbL, 65536, k2); stage4(gbH, 81920, k2);
        RDFRAG(af0, bf0, aB0, bB0, 32768); // Y.k0 (under MFMA below)
        MM64(af1, bf1);

        // ---- tile 2i+1 in bufY
        RDFRAG(af1, bf1, aB1, bB1, 32768); // Y.k1
        MM64(af0, bf0);
        LGKM0();                          // Y fully read
        VMW(0);                           // t+2 (bufX) landed
        BAR();
        stage4(gaL, 32768, k3);  stage4(gaH, 49152, k3);     // t+3 -> Y
        stage4(gbL, 98304, k3);  stage4(gbH, 114688, k3);
        RDFRAG(af0, bf0, aB0, bB0, 0);    // X.k0 (tile 2i+2)
        MM64(af1, bf1);
    }
    VMW(0);                  // drain wrapped stages before exit

    // ---- epilogue: bias + relu + bf16 store
    float bv[8];
#pragma unroll
    for (int g = 0; g < 8; ++g)
        bv[g] = bias[bn + wcol * 128 + g * 16 + l16];

#pragma unroll
    for (int f = 0; f < 8; ++f) {
        const int row0 = bm + wr * 128 + f * 16 + quad * 4;
#pragma unroll
        for (int g = 0; g < 8; ++g) {
            const int col = bn + wcol * 128 + g * 16 + l16;
#pragma unroll
            for (int r = 0; r < 4; ++r) {
                float v = fmaxf(acc[f][g][r] + bv[g], 0.0f);
                C[(size_t)(row0 + r) * N + col] = f2bf(v);
            }
        }
    }
}

// ---------------------------------------------------------------------------
// G4 + head fused: h4 = relu(A @ W4^T + b4) is NOT stored; each block
// computes partial dot(h4_row, Wo_cols) and atomicAdds into out[row].
// out pre-initialized to bo in prep_kernel. Block tile 128x128, acc[4][4].
// (unchanged -- ~20us, low-risk)
// ---------------------------------------------------------------------------
__global__ __launch_bounds__(256, 2)
void gemm_bt_head(const unsigned short* __restrict__ A,
                  const unsigned short* __restrict__ B,
                  const float* __restrict__ bias,
                  const float* __restrict__ Wo,
                  float* __restrict__ out,
                  int M, int N, int K)
{
    constexpr int BN = 128;
    constexpr int JT = 4;
    __shared__ __align__(16) unsigned short As[128 * BK];
    __shared__ __align__(16) unsigned short Bs[BN * BK];

    const int tid  = threadIdx.x;
    const int lane = tid & 63;
    const int wave = tid >> 6;
    const int quad = lane >> 4;
    const int l16  = lane & 15;

    const int bm = blockIdx.x * 128;
    const int bn = blockIdx.y * BN;
    const int wm = (wave & 1) * 64;
    const int wn = (wave >> 1) * 64;

    const int lrow = tid >> 3;
    const int gcol = ((tid & 7) ^ (lrow & 7)) * 8;

    const unsigned short* gaBase = A + (size_t)(bm + lrow) * K + gcol;
    const unsigned short* gbBase = B + (size_t)(bn + lrow) * K + gcol;

    unsigned short* lA = As + tid * 8;
    unsigned short* lB = Bs + tid * 8;

    const int xa = l16 & 7;
    const unsigned short* As_w = As + (wm + l16) * BK;
    const unsigned short* Bs_w = Bs + (wn + l16) * BK;
    const int c0 = (quad ^ xa) * 8;
    const int c1 = ((quad ^ 4) ^ xa) * 8;

    f32x4 acc[4][JT] = {};

    for (int k0 = 0; k0 < K; k0 += BK) {
#pragma unroll
        for (int i = 0; i < 4; ++i)
            async16(gaBase + (size_t)(i * 32) * K + k0, lA + i * 2048);
#pragma unroll
        for (int i = 0; i < JT; ++i)
            async16(gbBase + (size_t)(i * 32) * K + k0, lB + i * 2048);
        __syncthreads();

#pragma unroll
        for (int kk = 0; kk < 2; ++kk) {
            const int cs = kk ? c1 : c0;
            bf16x8 af[4], bfr[JT];
#pragma unroll
            for (int i = 0; i < 4; ++i)  af[i]  = *(const bf16x8*)(As_w + i * 16 * BK + cs);
#pragma unroll
            for (int j = 0; j < JT; ++j) bfr[j] = *(const bf16x8*)(Bs_w + j * 16 * BK + cs);
#pragma unroll
            for (int i = 0; i < 4; ++i)
#pragma unroll
                for (int j = 0; j < JT; ++j)
                    acc[i][j] = __builtin_amdgcn_mfma_f32_16x16x32_bf16(
                        af[i], bfr[j], acc[i][j], 0, 0, 0);
        }
        __syncthreads();
    }

    float bv[JT], wov[JT];
#pragma unroll
    for (int j = 0; j < JT; ++j) {
        const int col = bn + wn + j * 16 + l16;
        bv[j]  = bias[col];
        wov[j] = Wo[col];
    }

#pragma unroll
    for (int i = 0; i < 4; ++i) {
#pragma unroll
        for (int r = 0; r < 4; ++r) {
            float ws = 0.f;
#pragma unroll
            for (int j = 0; j < JT; ++j) {
                float v = acc[i][j][r] + bv[j];
                v = fmaxf(v, 0.0f);
                ws += v * wov[j];
            }
#pragma unroll
            for (int off = 8; off > 0; off >>= 1)
                ws += __shfl_xor(ws, off, 64);
            if (l16 == 0) {
                const int row = bm + wm + i * 16 + quad * 4 + r;
                atomicAdd(&out[row], ws);
            }
        }
    }
}

// ---------------------------------------------------------------------------
// Merged prep: [0,7680) convert W1..W4 fp32->bf16; [7680,11776) cross layer;
// [11776,11840) init out[m] = bo.   (unchanged)
// ---------------------------------------------------------------------------
__global__ __launch_bounds__(256)
void prep_kernel(const float* __restrict__ x, const float* __restrict__ cw,
                 const float* __restrict__ cb, unsigned short* __restrict__ h0,
                 const float* __restrict__ s1, const float* __restrict__ s2,
                 const float* __restrict__ s3, const float* __restrict__ s4,
                 unsigned short* __restrict__ d1, unsigned short* __restrict__ d2,
                 unsigned short* __restrict__ d3, unsigned short* __restrict__ d4,
                 const float* __restrict__ bo, float* __restrict__ out)
{
    const int b = blockIdx.x;
    if (b < 7680) {
        long t = (long)b * 256 + threadIdx.x;
        const float* s; unsigned short* d; long off;
        if (t < 262144L)       { s = s1; d = d1; off = t; }
        else if (t < 1310720L) { s = s2; d = d2; off = t - 262144L; }
        else if (t < 1835008L) { s = s3; d = d3; off = t - 1310720L; }
        else                   { s = s4; d = d4; off = t - 1835008L; }
        f32x4 f = *(const f32x4*)(s + off * 4);
        u16x4 o;
#pragma unroll
        for (int i = 0; i < 4; ++i) o[i] = f2bf(f[i]);
        *(u16x4*)(d + off * 4) = o;
    } else if (b < 11776) {
        const int row  = (b - 7680) * 4 + (threadIdx.x >> 6);
        const int lane = threadIdx.x & 63;
        const float* xr = x + (size_t)row * 512;
        float xv[8];
        float s = 0.f;
#pragma unroll
        for (int i = 0; i < 8; ++i) {
            const int c = lane + i * 64;
            xv[i] = xr[c];
            s += xv[i] * cw[c];
        }
#pragma unroll
        for (int off = 32; off > 0; off >>= 1) s += __shfl_down(s, off, 64);
        s = __shfl(s, 0, 64);
        unsigned short* hr = h0 + (size_t)row * 512;
#pragma unroll
        for (int i = 0; i < 8; ++i) {
            const int c = lane + i * 64;
            hr[c] = f2bf(xv[i] * s + cb[c] + xv[i]);
        }
    } else {
        const int t = (b - 11776) * 256 + threadIdx.x;   // 64 blocks = 16384
        out[t] = bo[0];
    }
}

// ---------------------------------------------------------------------------
extern "C" void kernel_launch(void* const* d_in, const int* in_sizes, int n_in,
                              void* d_out, int out_size, void* d_ws, size_t ws_size,
                              hipStream_t stream)
{
    const float* x  = (const float*)d_in[0];
    const float* cw = (const float*)d_in[1];
    const float* cb = (const float*)d_in[2];
    const float* W1 = (const float*)d_in[3];  const float* b1 = (const float*)d_in[4];
    const float* W2 = (const float*)d_in[5];  const float* b2 = (const float*)d_in[6];
    const float* W3 = (const float*)d_in[7];  const float* b3 = (const float*)d_in[8];
    const float* W4 = (const float*)d_in[9];  const float* b4 = (const float*)d_in[10];
    const float* Wo = (const float*)d_in[11]; const float* bo = (const float*)d_in[12];
    float* out = (float*)d_out;

    // workspace carve (~143 MB)
    char* p = (char*)d_ws;
    unsigned short* wb1 = (unsigned short*)p; p += (size_t)2048 * 512  * 2;
    unsigned short* wb2 = (unsigned short*)p; p += (size_t)2048 * 2048 * 2;
    unsigned short* wb3 = (unsigned short*)p; p += (size_t)1024 * 2048 * 2;
    unsigned short* wb4 = (unsigned short*)p; p += (size_t)512  * 1024 * 2;
    unsigned short* actA = (unsigned short*)p; p += (size_t)16384 * 2048 * 2; // h0,h2
    unsigned short* actB = (unsigned short*)p;                                // h1,h3

    prep_kernel<<<11840, 256, 0, stream>>>(x, cw, cb, actA,
                                           W1, W2, W3, W4, wb1, wb2, wb3, wb4,
                                           bo, out);

    // h1 = relu(h0 @ W1^T + b1)   [16384,2048], K=512
    gemm_fat_bias_relu<<<dim3(64, 8), 256, 0, stream>>>(actA, wb1, b1, actB, 16384, 2048, 512);
    // h2 = relu(h1 @ W2^T + b2)   [16384,2048], K=2048
    gemm_fat_bias_relu<<<dim3(64, 8), 256, 0, stream>>>(actB, wb2, b2, actA, 16384, 2048, 2048);
    // h3 = relu(h2 @ W3^T + b3)   [16384,1024], K=2048
    gemm_fat_bias_relu<<<dim3(64, 4), 256, 0, stream>>>(actA, wb3, b3, actB, 16384, 1024, 2048);
    // out += sum_cols relu(h3 @ W4^T + b4) * Wo   [16384,512] fused head
    gemm_bt_head<<<dim3(128, 4), 256, 0, stream>>>(actB, wb4, b4, Wo, out, 16384, 512, 1024);
}